// Round 1
// baseline (16.938 us; speedup 1.0000x reference)
//
#include <hip/hip_runtime.h>

// Potts model: out[b] = sum_t coeffs[t] * (x[b,idx[t,0..3]] all equal)
// B=2048, N=4096, T=8192, K=4, states in {0,1,2} stored as exact floats.
//
// Strategy: block owns G=8 rows of x. Pack the 8 rows byte-wise into LDS:
// xs[n] = u64 whose byte g is (uint8)x[b0+g][n]. Each thread strides over t,
// gathers 4 u64s, XOR-trick computes per-byte all-equal for 8 b's at once.

#define N_CONST 4096
#define G 8
#define THREADS 512

typedef unsigned long long u64;

__global__ __launch_bounds__(THREADS) void potts_kernel(
    const float* __restrict__ x,
    const float* __restrict__ coeffs,
    const int*   __restrict__ idx,
    float*       __restrict__ out,
    int Nn, int Tn)
{
    __shared__ u64 xs[N_CONST];
    __shared__ float red[THREADS / 64][G];

    const int tid = threadIdx.x;
    const int b0  = blockIdx.x * G;

    // Stage G rows of x into LDS, packed as bytes (values are exact 0/1/2).
    for (int n = tid; n < Nn; n += THREADS) {
        u64 v = 0;
        #pragma unroll
        for (int g = 0; g < G; ++g) {
            float f = x[(size_t)(b0 + g) * Nn + n];
            v |= (u64)((unsigned)(int)f & 0xFFu) << (8 * g);
        }
        xs[n] = v;
    }
    __syncthreads();

    float acc[G];
    #pragma unroll
    for (int g = 0; g < G; ++g) acc[g] = 0.f;

    for (int t = tid; t < Tn; t += THREADS) {
        const int4 ii = *reinterpret_cast<const int4*>(idx + 4 * t);
        const float c = coeffs[t];
        const u64 a  = xs[ii.x];
        const u64 b  = xs[ii.y];
        const u64 cc = xs[ii.z];
        const u64 d  = xs[ii.w];
        const u64 diff = (a ^ b) | (a ^ cc) | (a ^ d);
        #pragma unroll
        for (int g = 0; g < G; ++g) {
            acc[g] += ((((diff >> (8 * g)) & 0xFFull) == 0ull) ? c : 0.f);
        }
    }

    // Reduce across the block: wave shuffle, then tiny LDS reduce.
    #pragma unroll
    for (int g = 0; g < G; ++g) {
        float v = acc[g];
        #pragma unroll
        for (int off = 32; off > 0; off >>= 1) v += __shfl_down(v, off, 64);
        if ((tid & 63) == 0) red[tid >> 6][g] = v;
    }
    __syncthreads();

    if (tid < G) {
        float s = 0.f;
        #pragma unroll
        for (int w = 0; w < THREADS / 64; ++w) s += red[w][tid];
        out[b0 + tid] = s;
    }
}

extern "C" void kernel_launch(void* const* d_in, const int* in_sizes, int n_in,
                              void* d_out, int out_size, void* d_ws, size_t ws_size,
                              hipStream_t stream) {
    const float* x      = (const float*)d_in[0];   // [B, N] f32
    const float* coeffs = (const float*)d_in[1];   // [T] f32
    const int*   idx    = (const int*)d_in[2];     // [T, K=4] i32

    float* out = (float*)d_out;                    // [B] f32

    const int Bn = in_sizes[0] / 4096;             // 2048
    const int Nn = 4096;
    const int Tn = in_sizes[1];                    // 8192

    const int grid = Bn / G;                       // 256 blocks
    potts_kernel<<<grid, THREADS, 0, stream>>>(x, coeffs, idx, out, Nn, Tn);
}